// Round 1
// 606.171 us; speedup vs baseline: 1.1025x; 1.1025x over previous
//
#include <hip/hip_runtime.h>
#include <hip/hip_bf16.h>

// Problem constants
#define B_   32
#define C_   256
#define HW_  1024
#define N_   32768      // B_*HW_
#define M_   2000
#define MP_  2048       // M padded (rows >= 2000 are zero)
#define K_   256

typedef __attribute__((ext_vector_type(8))) _Float16 f16x8;
typedef __attribute__((ext_vector_type(4))) float f32x4;

#define CAP_ENTRIES (256 * 1024)
#define KCAP 32

// ---------------- prep kernels ----------------

// mem*64 -> fp16 hi/lo split, [MP_][K_], zero-padded rows (GEMM1 B, K-major)
__global__ void prep_memS_kernel(const float* __restrict__ mem,
                                 _Float16* __restrict__ mh,
                                 _Float16* __restrict__ ml) {
  int m = blockIdx.x;           // 0..2047
  int c = threadIdx.x;          // 0..255
  float v = (m < M_) ? mem[m * K_ + c] * 64.0f : 0.0f;
  _Float16 h = (_Float16)v;
  mh[m * K_ + c] = h;
  ml[m * K_ + c] = (_Float16)(v - (float)h);
}

// q[n][c] f16 hi/lo from x[b][c][hw] (tile transpose through LDS).
// qhi/qlo live in the y OUTPUT region (dead until finalize) - ws stays small.
__global__ void prep_q_kernel(const float* __restrict__ x,
                              _Float16* __restrict__ qhi,
                              _Float16* __restrict__ qlo) {
  __shared__ float t[32][33];
  int hw0 = blockIdx.x * 32;    // 32 blocks
  int c0  = blockIdx.y * 32;    // 8 blocks
  int b   = blockIdx.z;         // 32 blocks
  int li = threadIdx.x >> 5;
  int lj = threadIdx.x & 31;
  const float* xb = x + (size_t)b * C_ * HW_;
#pragma unroll
  for (int it = 0; it < 4; ++it) {
    int c = li + it * 8;
    t[c][lj] = xb[(size_t)(c0 + c) * HW_ + hw0 + lj];
  }
  __syncthreads();
#pragma unroll
  for (int it = 0; it < 4; ++it) {
    int n = li + it * 8;
    float v = t[lj][n];
    _Float16 h = (_Float16)v;
    size_t idx = (size_t)(b * HW_ + hw0 + n) * K_ + c0 + lj;
    qhi[idx] = h;
    qlo[idx] = (_Float16)(v - (float)h);
  }
}

// ---------------- K1: 3-pass fp16-split GEMM1 (m97 structure) ----------------
// 128n x 128m tile per WG, virtual K = 768 (hh, lh, hl), BK=64,
// global_load_lds width-16 staging. Epilogue: e=exp(64*logit * 2^-6) ->
// fp32 store to eb[n][2000]. (S is now computed in finalize from eb.)
// XCD-aware chunked swizzle: all 16 m-blocks of an n-block land on one XCD
// so the A panel (q tile) stays in that XCD's L2 (T1; 4096 % 8 == 0 ->
// bijective).
__global__ __launch_bounds__(256, 3) void gemm1_kernel(
    const _Float16* __restrict__ qhi, const _Float16* __restrict__ qlo,
    const _Float16* __restrict__ mh, const _Float16* __restrict__ ml,
    float* __restrict__ eb) {
  __shared__ _Float16 As[128 * 64];   // 16 KB
  __shared__ _Float16 Bs[128 * 64];   // 16 KB

  const int tid   = threadIdx.x;
  const int lane  = tid & 63;
  const int wave  = tid >> 6;        // 0..3
  const int row16 = lane & 15;
  const int quad  = lane >> 4;
  const int wr    = wave >> 1;       // n-half of wave
  const int wc    = wave & 1;        // m-half of wave

  // chunked XCD swizzle: orig linear id round-robins XCDs; give each XCD a
  // contiguous 512-WG chunk = 32 n-blocks x 16 m-blocks.
  const int wgid = blockIdx.y * gridDim.x + blockIdx.x;   // 0..4095
  const int swz  = (wgid & 7) * 512 + (wgid >> 3);        // bijective
  const int m0 = (swz & 15) * 128;
  const int n0 = (swz >> 4) * 128;

  f32x4 acc[4][4];
#pragma unroll
  for (int i = 0; i < 4; ++i)
#pragma unroll
    for (int j = 0; j < 4; ++j) acc[i][j] = (f32x4){0.f, 0.f, 0.f, 0.f};

  const int srow = tid >> 3;          // 0..31 (staging row within 32-row slab)
  const int scol = (tid & 7) * 8;     // halves; dst LDS addr = lane*16B (wave-uniform+lane pattern)

  for (int ch = 0; ch < 12; ++ch) {
    const int ph = ch >> 2;           // 0: hh, 1: lh, 2: hl
    const int k0 = (ch & 3) * 64;
    const _Float16* Ag = (ph == 1) ? qlo : qhi;
    const _Float16* Bg = (ph == 2) ? ml : mh;

    // stage A,B tiles: 4 + 4 global_load_lds dwordx4 per thread
#pragma unroll
    for (int i = 0; i < 4; ++i) {
      int row = i * 32 + srow;
      const _Float16* srcA = Ag + (size_t)(n0 + row) * K_ + k0 + scol;
      __builtin_amdgcn_global_load_lds(
          (const __attribute__((address_space(1))) unsigned int*)srcA,
          (__attribute__((address_space(3))) unsigned int*)(As + row * 64 + scol),
          16, 0, 0);
    }
#pragma unroll
    for (int i = 0; i < 4; ++i) {
      int row = i * 32 + srow;
      const _Float16* srcB = Bg + (size_t)(m0 + row) * K_ + k0 + scol;
      __builtin_amdgcn_global_load_lds(
          (const __attribute__((address_space(1))) unsigned int*)srcB,
          (__attribute__((address_space(3))) unsigned int*)(Bs + row * 64 + scol),
          16, 0, 0);
    }
    __syncthreads();

#pragma unroll
    for (int kk = 0; kk < 2; ++kk) {
      f16x8 af[4], bf[4];
#pragma unroll
      for (int t = 0; t < 4; ++t)
        af[t] = *(const f16x8*)(As + (wr * 64 + t * 16 + row16) * 64 + kk * 32 + quad * 8);
#pragma unroll
      for (int t = 0; t < 4; ++t)
        bf[t] = *(const f16x8*)(Bs + (wc * 64 + t * 16 + row16) * 64 + kk * 32 + quad * 8);
#pragma unroll
      for (int i = 0; i < 4; ++i)
#pragma unroll
        for (int j = 0; j < 4; ++j)
          acc[i][j] = __builtin_amdgcn_mfma_f32_16x16x32_f16(af[i], bf[j], acc[i][j], 0, 0, 0);
    }
    __syncthreads();
  }

  // epilogue: exp + store only (no S reduction / atomics any more)
  const int mbase = m0 + wc * 64 + row16;
#pragma unroll
  for (int i = 0; i < 4; ++i) {
    const int nb = n0 + wr * 64 + i * 16 + quad * 4;
#pragma unroll
    for (int j = 0; j < 4; ++j) {
      const int mg = mbase + j * 16;
      if (mg < M_) {
#pragma unroll
        for (int r = 0; r < 4; ++r) {
          float e = __expf(acc[i][j][r] * 0.015625f);
          eb[(size_t)(nb + r) * M_ + mg] = e;
        }
      }
    }
  }
}

// ---------------- K3: row-batched threshold + sparse GEMM2 + entry list ----
// Per WG: 32 pixel rows, one wave handles 4 rows. Per row: load the WHOLE
// 2000-float row as 8x float4 per lane (batched issue -> one HBM round trip
// instead of 32 serialized ones), reduce S in-register, threshold scan on
// registers, collect kept (m,p) in LDS, S2 = sum kept. Then
// y[c][hw] = sum_kept p*mem[m][c] / S2 (sparse) + append normalized entries.
__global__ __launch_bounds__(512) void finalize_kernel(
    const float* __restrict__ eb,
    const float* __restrict__ mem, float* __restrict__ y,
    uint2* __restrict__ entries, unsigned int* __restrict__ cnt) {
  __shared__ unsigned int kcnt[32];
  __shared__ unsigned int km[32][KCAP];
  __shared__ float kp[32][KCAP];
  __shared__ float kinv[32];

  const int tid  = threadIdx.x;
  const int lane = tid & 63;
  const int wave = tid >> 6;       // 0..7
  const int n0 = blockIdx.x * 32;

  // phase 1: batched row load + in-register threshold scan (4 rows per wave)
#pragma unroll 1
  for (int rr = 0; rr < 4; ++rr) {
    const int rw = wave * 4 + rr;
    const int n = n0 + rw;
    const float* er = eb + (size_t)n * M_;   // 2000 floats = 500 float4, 16B-aligned

    f32x4 v[8];
#pragma unroll
    for (int it = 0; it < 8; ++it) {
      const int j4 = it * 64 + lane;
      if (j4 < 500) v[it] = *(const f32x4*)(er + (size_t)j4 * 4);
      else          v[it] = (f32x4){0.f, 0.f, 0.f, 0.f};
    }

    // softmax denominator S = full row sum (register + wave reduce)
    float s = 0.f;
#pragma unroll
    for (int it = 0; it < 8; ++it)
      s += (v[it][0] + v[it][1]) + (v[it][2] + v[it][3]);
#pragma unroll
    for (int off = 32; off >= 1; off >>= 1) s += __shfl_xor(s, off, 64);

    const float thr = 0.0025f * s;
    float s2 = 0.f;
    unsigned int c = 0;
#pragma unroll
    for (int it = 0; it < 8; ++it) {
#pragma unroll
      for (int cc = 0; cc < 4; ++cc) {
        const float val = v[it][cc];
        unsigned long long mask = __ballot(val > thr);
        while (mask) {
          const int src = __builtin_ctzll(mask);
          mask &= mask - 1;
          const float p = __shfl(val, src, 64);
          if (lane == 0 && c < (unsigned)KCAP) {
            km[rw][c] = (unsigned)((it * 64 + src) * 4 + cc);
            kp[rw][c] = p;
          }
          ++c;
          s2 += p;
        }
      }
    }
    if (lane == 0) {
      kcnt[rw] = (c < (unsigned)KCAP) ? c : (unsigned)KCAP;
      kinv[rw] = (s2 > 0.f) ? (1.0f / s2) : 0.f;
    }
  }
  __syncthreads();

  // append normalized entries for scatter
  if (tid < 32) {
    const int n = n0 + tid;
    const unsigned int kc = kcnt[tid];
    if (kc) {
      unsigned int base = atomicAdd(cnt, kc);
      for (unsigned int k = 0; k < kc && base + k < (unsigned)CAP_ENTRIES; ++k) {
        uint2 e;
        e.x = ((unsigned)n << 11) | km[tid][k];
        e.y = __float_as_uint(kp[tid][k] * kinv[tid]);
        entries[base + k] = e;
      }
    }
  }

  // phase 2: sparse y. thread covers (c = ci*16 + tid>>5, hw row = tid&31)
  {
    const int hwL = tid & 31;
    const int cq  = tid >> 5;        // 0..15
    const int n = n0 + hwL;
    const int b = n >> 10;
    const int hw = n & 1023;
    const unsigned int kc = kcnt[hwL];
    const float inv = kinv[hwL];
    float* yb = y + (size_t)b * C_ * HW_ + hw;
#pragma unroll 1
    for (int ci = 0; ci < 16; ++ci) {
      const int c = ci * 16 + cq;
      float yv = 0.f;
      for (unsigned int k = 0; k < kc; ++k)
        yv += kp[hwL][k] * mem[(size_t)km[hwL][k] * K_ + c];
      yb[(size_t)c * HW_] = yv * inv;
    }
  }
}

// ---------------- scatter: att_out[b][m][hw] = p for kept entries ----------
__global__ void scatter_kernel(const uint2* __restrict__ entries,
                               const unsigned int* __restrict__ cnt,
                               float* __restrict__ att_out) {
  unsigned int t = blockIdx.x * 256 + threadIdx.x;
  unsigned int n = *cnt;
  if (n > (unsigned int)CAP_ENTRIES) n = (unsigned int)CAP_ENTRIES;
  if (t < n) {
    uint2 e = entries[t];
    unsigned int ng = e.x >> 11;
    unsigned int m  = e.x & 2047u;
    unsigned int b  = ng >> 10;
    unsigned int hw = ng & 1023u;
    att_out[(size_t)b * M_ * HW_ + (size_t)m * HW_ + hw] = __uint_as_float(e.y);
  }
}

// ---------------- host ----------------
extern "C" void kernel_launch(void* const* d_in, const int* in_sizes, int n_in,
                              void* d_out, int out_size, void* d_ws, size_t ws_size,
                              hipStream_t stream) {
  const float* x   = (const float*)d_in[0];      // [32,256,32,32]
  const float* mem = (const float*)d_in[1];      // [2000,256]
  float* y       = (float*)d_out;                              // 8388608 floats (33.55 MB)
  float* att_out = (float*)d_out + (size_t)B_ * C_ * HW_;      // 65536000 floats (262 MB)

  // q hi/lo (16 MB each) alias the y output region: written by prep_q, read
  // by gemm1, dead before finalize writes y. Keeps d_ws usage ~5 MB.
  _Float16* qhi = (_Float16*)y;
  _Float16* qlo = (_Float16*)((char*)y + (size_t)16 * 1024 * 1024);

  char* ws = (char*)d_ws;
  _Float16* mh  = (_Float16*)ws;                                   // 1 MB
  _Float16* ml  = (_Float16*)(ws + (size_t)1024 * 1024);           // 1 MB
  uint2* entries = (uint2*)(ws + (size_t)2 * 1024 * 1024);         // 2 MB
  unsigned int* cnt = (unsigned int*)(ws + (size_t)4 * 1024 * 1024);

  // e scratch aliases the att output region: [N_][M_] fp32 = exactly att bytes
  float* eb = att_out;

  prep_memS_kernel<<<dim3(MP_), dim3(K_), 0, stream>>>(mem, mh, ml);
  prep_q_kernel<<<dim3(HW_ / 32, C_ / 32, B_), dim3(256), 0, stream>>>(x, qhi, qlo);
  hipMemsetAsync(cnt, 0, sizeof(unsigned int), stream);

  gemm1_kernel<<<dim3(MP_ / 128, N_ / 128), dim3(256), 0, stream>>>(
      qhi, qlo, mh, ml, eb);
  finalize_kernel<<<dim3(N_ / 32), dim3(512), 0, stream>>>(
      eb, mem, y, entries, cnt);
  hipMemsetAsync(att_out, 0, (size_t)B_ * M_ * HW_ * sizeof(float), stream);
  scatter_kernel<<<dim3(CAP_ENTRIES / 256), dim3(256), 0, stream>>>(
      entries, cnt, att_out);
}

// Round 2
// 587.696 us; speedup vs baseline: 1.1372x; 1.0314x over previous
//
#include <hip/hip_runtime.h>
#include <hip/hip_bf16.h>

// Problem constants
#define B_   32
#define C_   256
#define HW_  1024
#define N_   32768      // B_*HW_
#define M_   2000
#define MP_  2048       // M padded (rows >= 2000 are zero)
#define K_   256

typedef __attribute__((ext_vector_type(8))) _Float16 f16x8;
typedef __attribute__((ext_vector_type(4))) float f32x4;

#define CAP_ENTRIES (256 * 1024)
#define KCAP 32

// ---------------- prep kernels ----------------

// mem*64 -> fp16 hi/lo split, [MP_][K_], zero-padded rows (GEMM1 B, K-major)
__global__ void prep_memS_kernel(const float* __restrict__ mem,
                                 _Float16* __restrict__ mh,
                                 _Float16* __restrict__ ml) {
  int m = blockIdx.x;           // 0..2047
  int c = threadIdx.x;          // 0..255
  float v = (m < M_) ? mem[m * K_ + c] * 64.0f : 0.0f;
  _Float16 h = (_Float16)v;
  mh[m * K_ + c] = h;
  ml[m * K_ + c] = (_Float16)(v - (float)h);
}

// q[n][c] f16 hi/lo from x[b][c][hw] (tile transpose through LDS).
// qhi/qlo live in the y OUTPUT region (dead until finalize) - ws stays small.
__global__ void prep_q_kernel(const float* __restrict__ x,
                              _Float16* __restrict__ qhi,
                              _Float16* __restrict__ qlo) {
  __shared__ float t[32][33];
  int hw0 = blockIdx.x * 32;    // 32 blocks
  int c0  = blockIdx.y * 32;    // 8 blocks
  int b   = blockIdx.z;         // 32 blocks
  int li = threadIdx.x >> 5;
  int lj = threadIdx.x & 31;
  const float* xb = x + (size_t)b * C_ * HW_;
#pragma unroll
  for (int it = 0; it < 4; ++it) {
    int c = li + it * 8;
    t[c][lj] = xb[(size_t)(c0 + c) * HW_ + hw0 + lj];
  }
  __syncthreads();
#pragma unroll
  for (int it = 0; it < 4; ++it) {
    int n = li + it * 8;
    float v = t[lj][n];
    _Float16 h = (_Float16)v;
    size_t idx = (size_t)(b * HW_ + hw0 + n) * K_ + c0 + lj;
    qhi[idx] = h;
    qlo[idx] = (_Float16)(v - (float)h);
  }
}

// ---------------- K1: merged-pass fp16-split GEMM1 ----------------
// 128n x 128m tile per WG. Per k-chunk (BK=64, 4 chunks): stage ALL FOUR
// operand tiles (Ah,Al,Bh,Bl = 64 KB LDS) once, then run the 3 precision
// passes (hh, lh, hl = 96 MFMAs) between ONE barrier pair.
// vs previous 12-chunk version: barrier-drains 24 -> 8 per WG, staged bytes
// 384 KB -> 256 KB. Cost: occupancy 3 -> 2 blocks/CU (LDS 64 KB).
// Epilogue: e = exp(64*logit * 2^-6) -> fp32 store to eb[n][2000].
// XCD-aware chunked swizzle: all 16 m-blocks of an n-block land on one XCD
// so the A panel (q tile) stays in that XCD's L2 (T1; 4096 % 8 == 0 ->
// bijective).
__global__ __launch_bounds__(256, 2) void gemm1_kernel(
    const _Float16* __restrict__ qhi, const _Float16* __restrict__ qlo,
    const _Float16* __restrict__ mh, const _Float16* __restrict__ ml,
    float* __restrict__ eb) {
  __shared__ _Float16 Ahs[128 * 64];  // 16 KB
  __shared__ _Float16 Als[128 * 64];  // 16 KB
  __shared__ _Float16 Bhs[128 * 64];  // 16 KB
  __shared__ _Float16 Bls[128 * 64];  // 16 KB

  const int tid   = threadIdx.x;
  const int lane  = tid & 63;
  const int wave  = tid >> 6;        // 0..3
  const int row16 = lane & 15;
  const int quad  = lane >> 4;
  const int wr    = wave >> 1;       // n-half of wave
  const int wc    = wave & 1;        // m-half of wave

  // chunked XCD swizzle: orig linear id round-robins XCDs; give each XCD a
  // contiguous 512-WG chunk = 32 n-blocks x 16 m-blocks.
  const int wgid = blockIdx.y * gridDim.x + blockIdx.x;   // 0..4095
  const int swz  = (wgid & 7) * 512 + (wgid >> 3);        // bijective
  const int m0 = (swz & 15) * 128;
  const int n0 = (swz >> 4) * 128;

  f32x4 acc[4][4];
#pragma unroll
  for (int i = 0; i < 4; ++i)
#pragma unroll
    for (int j = 0; j < 4; ++j) acc[i][j] = (f32x4){0.f, 0.f, 0.f, 0.f};

  const int srow = tid >> 3;          // 0..31 (staging row within 32-row slab)
  const int scol = (tid & 7) * 8;     // halves; dst LDS addr = lane*16B

  for (int ck = 0; ck < 4; ++ck) {
    const int k0 = ck * 64;

    // stage 4 tiles: 16 global_load_lds dwordx4 per thread
#pragma unroll
    for (int i = 0; i < 4; ++i) {
      const int row = i * 32 + srow;
      const size_t aoff = (size_t)(n0 + row) * K_ + k0 + scol;
      const size_t boff = (size_t)(m0 + row) * K_ + k0 + scol;
      const int loff = row * 64 + scol;
      __builtin_amdgcn_global_load_lds(
          (const __attribute__((address_space(1))) unsigned int*)(qhi + aoff),
          (__attribute__((address_space(3))) unsigned int*)(Ahs + loff), 16, 0, 0);
      __builtin_amdgcn_global_load_lds(
          (const __attribute__((address_space(1))) unsigned int*)(qlo + aoff),
          (__attribute__((address_space(3))) unsigned int*)(Als + loff), 16, 0, 0);
      __builtin_amdgcn_global_load_lds(
          (const __attribute__((address_space(1))) unsigned int*)(mh + boff),
          (__attribute__((address_space(3))) unsigned int*)(Bhs + loff), 16, 0, 0);
      __builtin_amdgcn_global_load_lds(
          (const __attribute__((address_space(1))) unsigned int*)(ml + boff),
          (__attribute__((address_space(3))) unsigned int*)(Bls + loff), 16, 0, 0);
    }
    __syncthreads();

#pragma unroll
    for (int kk = 0; kk < 2; ++kk) {
      const int akoff = kk * 32 + quad * 8;
      f16x8 ah[4], bh[4], al[4], bl[4];
#pragma unroll
      for (int t = 0; t < 4; ++t)
        ah[t] = *(const f16x8*)(Ahs + (wr * 64 + t * 16 + row16) * 64 + akoff);
#pragma unroll
      for (int t = 0; t < 4; ++t)
        bh[t] = *(const f16x8*)(Bhs + (wc * 64 + t * 16 + row16) * 64 + akoff);
      // pass hh
#pragma unroll
      for (int i = 0; i < 4; ++i)
#pragma unroll
        for (int j = 0; j < 4; ++j)
          acc[i][j] = __builtin_amdgcn_mfma_f32_16x16x32_f16(ah[i], bh[j], acc[i][j], 0, 0, 0);
#pragma unroll
      for (int t = 0; t < 4; ++t)
        al[t] = *(const f16x8*)(Als + (wr * 64 + t * 16 + row16) * 64 + akoff);
      // pass lh (Al x Bh)
#pragma unroll
      for (int i = 0; i < 4; ++i)
#pragma unroll
        for (int j = 0; j < 4; ++j)
          acc[i][j] = __builtin_amdgcn_mfma_f32_16x16x32_f16(al[i], bh[j], acc[i][j], 0, 0, 0);
#pragma unroll
      for (int t = 0; t < 4; ++t)
        bl[t] = *(const f16x8*)(Bls + (wc * 64 + t * 16 + row16) * 64 + akoff);
      // pass hl (Ah x Bl)
#pragma unroll
      for (int i = 0; i < 4; ++i)
#pragma unroll
        for (int j = 0; j < 4; ++j)
          acc[i][j] = __builtin_amdgcn_mfma_f32_16x16x32_f16(ah[i], bl[j], acc[i][j], 0, 0, 0);
    }
    __syncthreads();
  }

  // epilogue: exp + store
  const int mbase = m0 + wc * 64 + row16;
#pragma unroll
  for (int i = 0; i < 4; ++i) {
    const int nb = n0 + wr * 64 + i * 16 + quad * 4;
#pragma unroll
    for (int j = 0; j < 4; ++j) {
      const int mg = mbase + j * 16;
      if (mg < M_) {
#pragma unroll
        for (int r = 0; r < 4; ++r) {
          float e = __expf(acc[i][j][r] * 0.015625f);
          eb[(size_t)(nb + r) * M_ + mg] = e;
        }
      }
    }
  }
}

// ---------------- K3: row-batched threshold + sparse GEMM2 + entry list ----
// Per WG: 32 pixel rows, one wave handles 4 rows. Per row: load the WHOLE
// 2000-float row as 8x float4 per lane (batched issue -> one HBM round trip
// instead of 32 serialized ones), reduce S in-register, threshold scan on
// registers, collect kept (m,p) in LDS, S2 = sum kept. Then
// y[c][hw] = sum_kept p*mem[m][c] / S2 (sparse) + append normalized entries.
__global__ __launch_bounds__(512) void finalize_kernel(
    const float* __restrict__ eb,
    const float* __restrict__ mem, float* __restrict__ y,
    uint2* __restrict__ entries, unsigned int* __restrict__ cnt) {
  __shared__ unsigned int kcnt[32];
  __shared__ unsigned int km[32][KCAP];
  __shared__ float kp[32][KCAP];
  __shared__ float kinv[32];

  const int tid  = threadIdx.x;
  const int lane = tid & 63;
  const int wave = tid >> 6;       // 0..7
  const int n0 = blockIdx.x * 32;

  // phase 1: batched row load + in-register threshold scan (4 rows per wave)
#pragma unroll 1
  for (int rr = 0; rr < 4; ++rr) {
    const int rw = wave * 4 + rr;
    const int n = n0 + rw;
    const float* er = eb + (size_t)n * M_;   // 2000 floats = 500 float4, 16B-aligned

    f32x4 v[8];
#pragma unroll
    for (int it = 0; it < 8; ++it) {
      const int j4 = it * 64 + lane;
      if (j4 < 500) v[it] = *(const f32x4*)(er + (size_t)j4 * 4);
      else          v[it] = (f32x4){0.f, 0.f, 0.f, 0.f};
    }

    // softmax denominator S = full row sum (register + wave reduce)
    float s = 0.f;
#pragma unroll
    for (int it = 0; it < 8; ++it)
      s += (v[it][0] + v[it][1]) + (v[it][2] + v[it][3]);
#pragma unroll
    for (int off = 32; off >= 1; off >>= 1) s += __shfl_xor(s, off, 64);

    const float thr = 0.0025f * s;
    float s2 = 0.f;
    unsigned int c = 0;
#pragma unroll
    for (int it = 0; it < 8; ++it) {
#pragma unroll
      for (int cc = 0; cc < 4; ++cc) {
        const float val = v[it][cc];
        unsigned long long mask = __ballot(val > thr);
        while (mask) {
          const int src = __builtin_ctzll(mask);
          mask &= mask - 1;
          const float p = __shfl(val, src, 64);
          if (lane == 0 && c < (unsigned)KCAP) {
            km[rw][c] = (unsigned)((it * 64 + src) * 4 + cc);
            kp[rw][c] = p;
          }
          ++c;
          s2 += p;
        }
      }
    }
    if (lane == 0) {
      kcnt[rw] = (c < (unsigned)KCAP) ? c : (unsigned)KCAP;
      kinv[rw] = (s2 > 0.f) ? (1.0f / s2) : 0.f;
    }
  }
  __syncthreads();

  // append normalized entries for scatter
  if (tid < 32) {
    const int n = n0 + tid;
    const unsigned int kc = kcnt[tid];
    if (kc) {
      unsigned int base = atomicAdd(cnt, kc);
      for (unsigned int k = 0; k < kc && base + k < (unsigned)CAP_ENTRIES; ++k) {
        uint2 e;
        e.x = ((unsigned)n << 11) | km[tid][k];
        e.y = __float_as_uint(kp[tid][k] * kinv[tid]);
        entries[base + k] = e;
      }
    }
  }

  // phase 2: sparse y. thread covers (c = ci*16 + tid>>5, hw row = tid&31)
  {
    const int hwL = tid & 31;
    const int cq  = tid >> 5;        // 0..15
    const int n = n0 + hwL;
    const int b = n >> 10;
    const int hw = n & 1023;
    const unsigned int kc = kcnt[hwL];
    const float inv = kinv[hwL];
    float* yb = y + (size_t)b * C_ * HW_ + hw;
#pragma unroll 1
    for (int ci = 0; ci < 16; ++ci) {
      const int c = ci * 16 + cq;
      float yv = 0.f;
      for (unsigned int k = 0; k < kc; ++k)
        yv += kp[hwL][k] * mem[(size_t)km[hwL][k] * K_ + c];
      yb[(size_t)c * HW_] = yv * inv;
    }
  }
}

// ---------------- scatter: att_out[b][m][hw] = p for kept entries ----------
__global__ void scatter_kernel(const uint2* __restrict__ entries,
                               const unsigned int* __restrict__ cnt,
                               float* __restrict__ att_out) {
  unsigned int t = blockIdx.x * 256 + threadIdx.x;
  unsigned int n = *cnt;
  if (n > (unsigned int)CAP_ENTRIES) n = (unsigned int)CAP_ENTRIES;
  if (t < n) {
    uint2 e = entries[t];
    unsigned int ng = e.x >> 11;
    unsigned int m  = e.x & 2047u;
    unsigned int b  = ng >> 10;
    unsigned int hw = ng & 1023u;
    att_out[(size_t)b * M_ * HW_ + (size_t)m * HW_ + hw] = __uint_as_float(e.y);
  }
}

// ---------------- host ----------------
extern "C" void kernel_launch(void* const* d_in, const int* in_sizes, int n_in,
                              void* d_out, int out_size, void* d_ws, size_t ws_size,
                              hipStream_t stream) {
  const float* x   = (const float*)d_in[0];      // [32,256,32,32]
  const float* mem = (const float*)d_in[1];      // [2000,256]
  float* y       = (float*)d_out;                              // 8388608 floats (33.55 MB)
  float* att_out = (float*)d_out + (size_t)B_ * C_ * HW_;      // 65536000 floats (262 MB)

  // q hi/lo (16 MB each) alias the y output region: written by prep_q, read
  // by gemm1, dead before finalize writes y. Keeps d_ws usage ~5 MB.
  _Float16* qhi = (_Float16*)y;
  _Float16* qlo = (_Float16*)((char*)y + (size_t)16 * 1024 * 1024);

  char* ws = (char*)d_ws;
  _Float16* mh  = (_Float16*)ws;                                   // 1 MB
  _Float16* ml  = (_Float16*)(ws + (size_t)1024 * 1024);           // 1 MB
  uint2* entries = (uint2*)(ws + (size_t)2 * 1024 * 1024);         // 2 MB
  unsigned int* cnt = (unsigned int*)(ws + (size_t)4 * 1024 * 1024);

  // e scratch aliases the att output region: [N_][M_] fp32 = exactly att bytes
  float* eb = att_out;

  prep_memS_kernel<<<dim3(MP_), dim3(K_), 0, stream>>>(mem, mh, ml);
  prep_q_kernel<<<dim3(HW_ / 32, C_ / 32, B_), dim3(256), 0, stream>>>(x, qhi, qlo);
  hipMemsetAsync(cnt, 0, sizeof(unsigned int), stream);

  gemm1_kernel<<<dim3(MP_ / 128, N_ / 128), dim3(256), 0, stream>>>(
      qhi, qlo, mh, ml, eb);
  finalize_kernel<<<dim3(N_ / 32), dim3(512), 0, stream>>>(
      eb, mem, y, entries, cnt);
  hipMemsetAsync(att_out, 0, (size_t)B_ * M_ * HW_ * sizeof(float), stream);
  scatter_kernel<<<dim3(CAP_ENTRIES / 256), dim3(256), 0, stream>>>(
      entries, cnt, att_out);
}